// Round 1
// baseline (192.343 us; speedup 1.0000x reference)
//
#include <hip/hip_runtime.h>

// Conv2d 3x3 s1 p1, N=16 C=64 H=W=112 F=64, fp32 in/out, bf16 MFMA implicit GEMM.
// One block = one (n,h) output row: 112 pixels x 64 cout. 4 waves, each wave
// owns a 16-wide cout slice across all 112 pixels (7 M-tiles of 16).

typedef __attribute__((ext_vector_type(8))) short bf16x8;
typedef __attribute__((ext_vector_type(4))) float f32x4;

#define CIN 64
#define COUT 64
#define HH 112
#define WW 112

// LDS input tile: bf16 [3 rows][114 wcols][c padded to 72]
#define XP 72
#define WCOLS 114
#define LDS_SHORTS (3 * WCOLS * XP)  // 24624 shorts = 49248 B
// epilogue reuse as float [64 f][113]
#define OP 113

__device__ __forceinline__ unsigned short f2bf(float f) {
    unsigned u = __builtin_bit_cast(unsigned, f);
    u += 0x7FFFu + ((u >> 16) & 1u);   // round-to-nearest-even
    return (unsigned short)(u >> 16);
}

__global__ __launch_bounds__(256, 3)
void conv3x3_mfma(const float* __restrict__ x, const float* __restrict__ wts,
                  const float* __restrict__ bias, float* __restrict__ out)
{
    __shared__ __align__(16) short lds[LDS_SHORTS];
    const int tid = threadIdx.x;
    const int h = blockIdx.x;
    const int n = blockIdx.y;

    // ---- zero the padding columns (wcol 0 and 113) for all dy, c ----
    if (tid < 192) {
        int dy = tid / 64;
        int rest = tid - dy * 64;
        int wcol = (rest >= 32) ? (WCOLS - 1) : 0;
        int c2 = rest & 31;
        *(unsigned*)&lds[(dy * WCOLS + wcol) * XP + c2 * 2] = 0u;
    }
    // ---- zero out-of-bounds input planes at image top/bottom ----
    if (h == 0) {
        for (int i = tid; i < WCOLS * 32; i += 256) {
            int wcol = i >> 5, c2 = i & 31;
            *(unsigned*)&lds[(0 * WCOLS + wcol) * XP + c2 * 2] = 0u;
        }
    }
    if (h == HH - 1) {
        for (int i = tid; i < WCOLS * 32; i += 256) {
            int wcol = i >> 5, c2 = i & 31;
            *(unsigned*)&lds[(2 * WCOLS + wcol) * XP + c2 * 2] = 0u;
        }
    }
    // ---- stage interior: 3 dy x 64 c rows, 28 float4 per row (112 w) ----
    // 192*28 = 5376 float4-loads; 5376/256 = 21 per thread, fully coalesced.
    for (int i = tid; i < 192 * 28; i += 256) {
        int row = i / 28;
        int w4 = i - row * 28;
        int dy = row >> 6;
        int c = row & 63;
        int gh = h + dy - 1;
        if ((unsigned)gh < (unsigned)HH) {
            const float4 v = *(const float4*)(x + (((n * CIN + c) * HH + gh) * WW + w4 * 4));
            int base = (dy * WCOLS + 1 + w4 * 4) * XP + c;
            lds[base         ] = (short)f2bf(v.x);
            lds[base + XP    ] = (short)f2bf(v.y);
            lds[base + 2 * XP] = (short)f2bf(v.z);
            lds[base + 3 * XP] = (short)f2bf(v.w);
        }
    }
    __syncthreads();

    const int wave = tid >> 6;
    const int lane = tid & 63;
    const int lm = lane & 15;          // A: pixel m ; B/D: cout col n
    const int lk = (lane >> 4) << 3;   // k-octet base (channel)

    f32x4 acc[7];
#pragma unroll
    for (int mt = 0; mt < 7; ++mt) acc[mt] = (f32x4){0.f, 0.f, 0.f, 0.f};

#pragma unroll
    for (int ky = 0; ky < 3; ++ky) {
#pragma unroll
        for (int kx = 0; kx < 3; ++kx) {
            // B fragments (weights) for this tap, c-blocks 0 and 1.
            // B[k=c][n=f]: f = wave*16 + lm, c = cb*32 + lk + j ; OIHW stride per c = 9.
            bf16x8 b0, b1;
            const float* wp = wts + ((((wave * 16 + lm) * CIN + lk) * 3 + ky) * 3 + kx);
#pragma unroll
            for (int j = 0; j < 8; ++j) {
                b0[j] = (short)f2bf(wp[j * 9]);
                b1[j] = (short)f2bf(wp[(j + 32) * 9]);
            }
#pragma unroll
            for (int mt = 0; mt < 7; ++mt) {
                // A[m=pixel][k=c]: wcol = w_out + kx (LDS col 0 == input col -1)
                int e = (ky * WCOLS + mt * 16 + lm + kx) * XP + lk;
                bf16x8 a0 = *(const bf16x8*)&lds[e];
                bf16x8 a1 = *(const bf16x8*)&lds[e + 32];
                acc[mt] = __builtin_amdgcn_mfma_f32_16x16x32_bf16(a0, b0, acc[mt], 0, 0, 0);
                acc[mt] = __builtin_amdgcn_mfma_f32_16x16x32_bf16(a1, b1, acc[mt], 0, 0, 0);
            }
        }
    }

    // ---- epilogue: transpose through LDS for coalesced fp32 stores ----
    __syncthreads();
    float* lout = (float*)lds;
#pragma unroll
    for (int mt = 0; mt < 7; ++mt) {
#pragma unroll
        for (int r = 0; r < 4; ++r) {
            int p = mt * 16 + ((lane >> 4) << 2) + r;   // D row = pixel
            lout[(wave * 16 + lm) * OP + p] = acc[mt][r];
        }
    }
    __syncthreads();
    for (int i = tid; i < 64 * 28; i += 256) {  // 7 iters: 64 f-rows x 28 float4
        int f = i / 28;
        int w4 = i - f * 28;
        float b = bias[f];
        const float* lp = lout + f * OP + w4 * 4;
        float4 v;
        v.x = lp[0] + b; v.y = lp[1] + b; v.z = lp[2] + b; v.w = lp[3] + b;
        *(float4*)(out + (((n * COUT + f) * HH + h) * WW + w4 * 4)) = v;
    }
}

extern "C" void kernel_launch(void* const* d_in, const int* in_sizes, int n_in,
                              void* d_out, int out_size, void* d_ws, size_t ws_size,
                              hipStream_t stream) {
    const float* x = (const float*)d_in[0];
    const float* w = (const float*)d_in[1];
    const float* b = (const float*)d_in[2];
    float* out = (float*)d_out;
    dim3 grid(HH, 16);  // (h, n)
    conv3x3_mfma<<<grid, 256, 0, stream>>>(x, w, b, out);
}

// Round 2
// 133.370 us; speedup vs baseline: 1.4422x; 1.4422x over previous
//
#include <hip/hip_runtime.h>

// Conv2d 3x3 s1 p1, N=16 C=64 H=W=112 F=64, fp32 in/out, bf16 MFMA implicit GEMM.
// One block = one (n,h) output row: 112 pixels x 64 cout. 4 waves, each wave
// owns a 16-wide cout slice across all 112 pixels (7 M-tiles of 16).
// R2: weights pre-converted to bf16 in B-fragment layout (coalesced dwordx4
// loads, no per-block conversion); staging writes channel-pair packed b32.

typedef __attribute__((ext_vector_type(8))) short bf16x8;
typedef __attribute__((ext_vector_type(4))) float f32x4;

#define CIN 64
#define COUT 64
#define HH 112
#define WW 112

// LDS input tile: bf16 [3 rows][114 wcols][c padded to 72]
#define XP 72
#define WCOLS 114
#define LDS_SHORTS (3 * WCOLS * XP)  // 24624 shorts = 49248 B
// epilogue reuse as float [64 f][113]
#define OP 113

__device__ __forceinline__ unsigned short f2bf(float f) {
    unsigned u = __builtin_bit_cast(unsigned, f);
    u += 0x7FFFu + ((u >> 16) & 1u);   // round-to-nearest-even
    return (unsigned short)(u >> 16);
}

// ---- one-time weight conversion: OIHW fp32 -> bf16 [t][cb][koct][f][j] ----
// dest flat index i: j=i&7, f=(i>>3)&63, koct=(i>>9)&3, cb=(i>>11)&1, t=i>>12
__global__ void conv_wprep(const float* __restrict__ w, short* __restrict__ wbf) {
    int i = blockIdx.x * 256 + threadIdx.x;    // grid sized to exactly 36864
    int j = i & 7;
    int f = (i >> 3) & 63;
    int koct = (i >> 9) & 3;
    int cb = (i >> 11) & 1;
    int t = i >> 12;
    int c = cb * 32 + koct * 8 + j;
    int ky = t / 3, kx = t - ky * 3;
    wbf[i] = (short)f2bf(w[((f * CIN + c) * 3 + ky) * 3 + kx]);
}

__global__ __launch_bounds__(256, 3)
void conv3x3_mfma(const float* __restrict__ x, const short* __restrict__ wbf,
                  const float* __restrict__ bias, float* __restrict__ out)
{
    __shared__ __align__(16) short lds[LDS_SHORTS];
    const int tid = threadIdx.x;
    const int h = blockIdx.x;
    const int n = blockIdx.y;

    // ---- zero the padding columns (wcol 0 and 113) for all dy, c ----
    if (tid < 192) {
        int dy = tid / 64;
        int rest = tid - dy * 64;
        int wcol = (rest >= 32) ? (WCOLS - 1) : 0;
        int c2 = rest & 31;
        *(unsigned*)&lds[(dy * WCOLS + wcol) * XP + c2 * 2] = 0u;
    }
    // ---- zero out-of-bounds input planes at image top/bottom ----
    if (h == 0) {
        for (int i = tid; i < WCOLS * 32; i += 256) {
            int wcol = i >> 5, c2 = i & 31;
            *(unsigned*)&lds[(0 * WCOLS + wcol) * XP + c2 * 2] = 0u;
        }
    }
    if (h == HH - 1) {
        for (int i = tid; i < WCOLS * 32; i += 256) {
            int wcol = i >> 5, c2 = i & 31;
            *(unsigned*)&lds[(2 * WCOLS + wcol) * XP + c2 * 2] = 0u;
        }
    }
    // ---- stage interior: 3 dy x 32 c-pairs, 28 float4-units per row ----
    // 96*28 = 2688 units; each: 2 coalesced float4 loads, 4 packed b32 LDS writes
    for (int i = tid; i < 96 * 28; i += 256) {
        int rp = i / 28;
        int w4 = i - rp * 28;
        int dy = rp >> 5;
        int c = (rp & 31) * 2;
        int gh = h + dy - 1;
        if ((unsigned)gh < (unsigned)HH) {
            const float* px = x + (((n * CIN + c) * HH + gh) * WW + w4 * 4);
            const float4 v0 = *(const float4*)px;
            const float4 v1 = *(const float4*)(px + HH * WW);
            int base = (dy * WCOLS + 1 + w4 * 4) * XP + c;
            unsigned p0 = (unsigned)f2bf(v0.x) | ((unsigned)f2bf(v1.x) << 16);
            unsigned p1 = (unsigned)f2bf(v0.y) | ((unsigned)f2bf(v1.y) << 16);
            unsigned p2 = (unsigned)f2bf(v0.z) | ((unsigned)f2bf(v1.z) << 16);
            unsigned p3 = (unsigned)f2bf(v0.w) | ((unsigned)f2bf(v1.w) << 16);
            *(unsigned*)&lds[base         ] = p0;
            *(unsigned*)&lds[base + XP    ] = p1;
            *(unsigned*)&lds[base + 2 * XP] = p2;
            *(unsigned*)&lds[base + 3 * XP] = p3;
        }
    }
    __syncthreads();

    const int wave = tid >> 6;
    const int lane = tid & 63;
    const int lm = lane & 15;          // A: pixel m ; B/D: cout col n
    const int lk = (lane >> 4) << 3;   // k-octet base (channel)

    // per-lane offset into wbf fragment tensor: [t][cb][koct][f][j]
    const short* wlane = wbf + ((lane >> 4) * 512 + (wave * 16 + lm) * 8);

    f32x4 acc[7];
#pragma unroll
    for (int mt = 0; mt < 7; ++mt) acc[mt] = (f32x4){0.f, 0.f, 0.f, 0.f};

#pragma unroll
    for (int ky = 0; ky < 3; ++ky) {
#pragma unroll
        for (int kx = 0; kx < 3; ++kx) {
            const int t = ky * 3 + kx;
            bf16x8 b0 = *(const bf16x8*)(wlane + t * 4096);
            bf16x8 b1 = *(const bf16x8*)(wlane + t * 4096 + 2048);
#pragma unroll
            for (int mt = 0; mt < 7; ++mt) {
                // A[m=pixel][k=c]: wcol = w_out + kx (LDS col 0 == input col -1)
                int e = (ky * WCOLS + mt * 16 + lm + kx) * XP + lk;
                bf16x8 a0 = *(const bf16x8*)&lds[e];
                bf16x8 a1 = *(const bf16x8*)&lds[e + 32];
                acc[mt] = __builtin_amdgcn_mfma_f32_16x16x32_bf16(a0, b0, acc[mt], 0, 0, 0);
                acc[mt] = __builtin_amdgcn_mfma_f32_16x16x32_bf16(a1, b1, acc[mt], 0, 0, 0);
            }
        }
    }

    // ---- epilogue: transpose through LDS for coalesced fp32 stores ----
    __syncthreads();
    float* lout = (float*)lds;
#pragma unroll
    for (int mt = 0; mt < 7; ++mt) {
#pragma unroll
        for (int r = 0; r < 4; ++r) {
            int p = mt * 16 + ((lane >> 4) << 2) + r;   // D row = pixel
            lout[(wave * 16 + lm) * OP + p] = acc[mt][r];
        }
    }
    __syncthreads();
    for (int i = tid; i < 64 * 28; i += 256) {  // 7 iters: 64 f-rows x 28 float4
        int f = i / 28;
        int w4 = i - f * 28;
        float b = bias[f];
        const float* lp = lout + f * OP + w4 * 4;
        float4 v;
        v.x = lp[0] + b; v.y = lp[1] + b; v.z = lp[2] + b; v.w = lp[3] + b;
        *(float4*)(out + (((n * COUT + f) * HH + h) * WW + w4 * 4)) = v;
    }
}

extern "C" void kernel_launch(void* const* d_in, const int* in_sizes, int n_in,
                              void* d_out, int out_size, void* d_ws, size_t ws_size,
                              hipStream_t stream) {
    const float* x = (const float*)d_in[0];
    const float* w = (const float*)d_in[1];
    const float* b = (const float*)d_in[2];
    float* out = (float*)d_out;
    short* wbf = (short*)d_ws;   // 36864 shorts = 73728 B

    conv_wprep<<<144, 256, 0, stream>>>(w, wbf);   // 144*256 == 36864 exactly
    dim3 grid(HH, 16);  // (h, n)
    conv3x3_mfma<<<grid, 256, 0, stream>>>(x, wbf, b, out);
}

// Round 3
// 125.310 us; speedup vs baseline: 1.5349x; 1.0643x over previous
//
#include <hip/hip_runtime.h>

// Conv2d 3x3 s1 p1, N=16 C=64 H=W=112 F=64, fp32 in/out, bf16 MFMA implicit GEMM.
// One block = one (n,h) output row: 112 pixels x 64 cout, 4 waves.
// R3: octet-XOR-swizzled LDS layout + b64 channel-quad staging writes (kills
// the 14-way write conflicts), grid transposed to (n,h) for same-XCD L2 reuse
// of input rows, B-fragment loads hoisted above staging.

typedef __attribute__((ext_vector_type(8))) short bf16x8;
typedef __attribute__((ext_vector_type(4))) float f32x4;

#define CIN 64
#define COUT 64
#define HH 112
#define WW 112

// LDS input tile: bf16 [3 rows][114 wcols][72 shorts/row-col (36 dwords)]
// Within a (dy,wcol) row: channel octet o (8 ch) lives at dword slot
//   4*(o ^ ((wcol>>2)&7)) .. +3   (slots 0..31 used; 32..35 pad)
#define XP 72
#define WCOLS 114
#define LDS_SHORTS (3 * WCOLS * XP)  // 24624 shorts = 49248 B
// epilogue reuse as float [64 f][113]
#define OP 113

__device__ __forceinline__ unsigned short f2bf(float f) {
    unsigned u = __builtin_bit_cast(unsigned, f);
    u += 0x7FFFu + ((u >> 16) & 1u);   // round-to-nearest-even
    return (unsigned short)(u >> 16);
}

// ---- one-time weight conversion: OIHW fp32 -> bf16 [t][cb][koct][f][j] ----
__global__ void conv_wprep(const float* __restrict__ w, short* __restrict__ wbf) {
    int i = blockIdx.x * 256 + threadIdx.x;    // grid sized to exactly 36864
    int j = i & 7;
    int f = (i >> 3) & 63;
    int koct = (i >> 9) & 3;
    int cb = (i >> 11) & 1;
    int t = i >> 12;
    int c = cb * 32 + koct * 8 + j;
    int ky = t / 3, kx = t - ky * 3;
    wbf[i] = (short)f2bf(w[((f * CIN + c) * 3 + ky) * 3 + kx]);
}

__global__ __launch_bounds__(256, 3)
void conv3x3_mfma(const float* __restrict__ x, const short* __restrict__ wbf,
                  const float* __restrict__ bias, float* __restrict__ out)
{
    __shared__ __align__(16) short lds[LDS_SHORTS];
    const int tid = threadIdx.x;
    const int n = blockIdx.x;
    const int h = blockIdx.y;

    const int wave = tid >> 6;
    const int lane = tid & 63;
    const int lm = lane & 15;          // A: pixel m ; B/D: cout col n
    const int q  = lane >> 4;          // k-octet index 0..3

    // ---- hoist B fragments: latency overlaps the staging phase ----
    const short* wlane = wbf + (q * 512 + (wave * 16 + lm) * 8);
    bf16x8 bfr[9][2];
#pragma unroll
    for (int t = 0; t < 9; ++t) {
        bfr[t][0] = *(const bf16x8*)(wlane + t * 4096);
        bfr[t][1] = *(const bf16x8*)(wlane + t * 4096 + 2048);
    }

    // ---- zero the padding columns (wcol 0 and 113): 32 dwords each row ----
    if (tid < 96) {
        int e = tid & 15;              // uint2 slot 0..15
        int g = tid >> 4;              // 0..5
        int dy = g >> 1;
        int wcol = (g & 1) ? (WCOLS - 1) : 0;
        *(uint2*)&lds[((dy * WCOLS + wcol) * 36 + e * 2) * 2] = (uint2){0u, 0u};
    }
    // ---- zero out-of-bounds input planes at image top/bottom ----
    if (h == 0) {
        for (int i = tid; i < WCOLS * 16; i += 256) {
            int wcol = i >> 4, e = i & 15;
            *(uint2*)&lds[((0 * WCOLS + wcol) * 36 + e * 2) * 2] = (uint2){0u, 0u};
        }
    }
    if (h == HH - 1) {
        for (int i = tid; i < WCOLS * 16; i += 256) {
            int wcol = i >> 4, e = i & 15;
            *(uint2*)&lds[((2 * WCOLS + wcol) * 36 + e * 2) * 2] = (uint2){0u, 0u};
        }
    }
    // ---- stage interior: 3 dy x 16 c-quads x 28 w4-units ----
    // each unit: 4 coalesced float4 loads (c..c+3), 4 swizzled b64 LDS writes
    for (int i = tid; i < 3 * 16 * 28; i += 256) {
        int w4 = i % 28;
        int rp = i / 28;               // 0..47
        int dy = rp >> 4;
        int cq = rp & 15;
        int gh = h + dy - 1;
        if ((unsigned)gh < (unsigned)HH) {
            int c = cq * 4;
            const float* px = x + (((n * CIN + c) * HH + gh) * WW + w4 * 4);
            const float4 v0 = *(const float4*)px;
            const float4 v1 = *(const float4*)(px + HH * WW);
            const float4 v2 = *(const float4*)(px + 2 * HH * WW);
            const float4 v3 = *(const float4*)(px + 3 * HH * WW);
            int o = cq >> 1, p = cq & 1;
            float a0[4] = {v0.x, v0.y, v0.z, v0.w};
            float a1[4] = {v1.x, v1.y, v1.z, v1.w};
            float a2[4] = {v2.x, v2.y, v2.z, v2.w};
            float a3[4] = {v3.x, v3.y, v3.z, v3.w};
#pragma unroll
            for (int dw = 0; dw < 4; ++dw) {
                int wcol = 1 + w4 * 4 + dw;
                int swz = (wcol >> 2) & 7;
                int dslot = 4 * (o ^ swz) + 2 * p;
                uint2 pk;
                pk.x = (unsigned)f2bf(a0[dw]) | ((unsigned)f2bf(a1[dw]) << 16);
                pk.y = (unsigned)f2bf(a2[dw]) | ((unsigned)f2bf(a3[dw]) << 16);
                *(uint2*)&lds[((dy * WCOLS + wcol) * 36 + dslot) * 2] = pk;
            }
        }
    }
    __syncthreads();

    f32x4 acc[7];
#pragma unroll
    for (int mt = 0; mt < 7; ++mt) acc[mt] = (f32x4){0.f, 0.f, 0.f, 0.f};

#pragma unroll
    for (int ky = 0; ky < 3; ++ky) {
#pragma unroll
        for (int kx = 0; kx < 3; ++kx) {
            const int t = ky * 3 + kx;
#pragma unroll
            for (int mt = 0; mt < 7; ++mt) {
                int wcol = mt * 16 + lm + kx;       // 0..113
                int swz = (wcol >> 2) & 7;
                int base = (ky * WCOLS + wcol) * XP;
                bf16x8 a0 = *(const bf16x8*)&lds[base + 8 * (q ^ swz)];
                bf16x8 a1 = *(const bf16x8*)&lds[base + 8 * ((q + 4) ^ swz)];
                acc[mt] = __builtin_amdgcn_mfma_f32_16x16x32_bf16(a0, bfr[t][0], acc[mt], 0, 0, 0);
                acc[mt] = __builtin_amdgcn_mfma_f32_16x16x32_bf16(a1, bfr[t][1], acc[mt], 0, 0, 0);
            }
        }
    }

    // ---- epilogue: transpose through LDS for coalesced fp32 stores ----
    __syncthreads();
    float* lout = (float*)lds;
#pragma unroll
    for (int mt = 0; mt < 7; ++mt) {
#pragma unroll
        for (int r = 0; r < 4; ++r) {
            int p = mt * 16 + (q << 2) + r;   // D row = pixel
            lout[(wave * 16 + lm) * OP + p] = acc[mt][r];
        }
    }
    __syncthreads();
    for (int i = tid; i < 64 * 28; i += 256) {  // 7 iters: 64 f-rows x 28 float4
        int f = i / 28;
        int w4 = i - f * 28;
        float b = bias[f];
        const float* lp = lout + f * OP + w4 * 4;
        float4 v;
        v.x = lp[0] + b; v.y = lp[1] + b; v.z = lp[2] + b; v.w = lp[3] + b;
        *(float4*)(out + (((n * COUT + f) * HH + h) * WW + w4 * 4)) = v;
    }
}

extern "C" void kernel_launch(void* const* d_in, const int* in_sizes, int n_in,
                              void* d_out, int out_size, void* d_ws, size_t ws_size,
                              hipStream_t stream) {
    const float* x = (const float*)d_in[0];
    const float* w = (const float*)d_in[1];
    const float* b = (const float*)d_in[2];
    float* out = (float*)d_out;
    short* wbf = (short*)d_ws;   // 36864 shorts = 73728 B

    conv_wprep<<<144, 256, 0, stream>>>(w, wbf);   // 144*256 == 36864 exactly
    dim3 grid(16, HH);  // (n, h): id%8 == n%8 -> row re-reads stay on one XCD
    conv3x3_mfma<<<grid, 256, 0, stream>>>(x, wbf, b, out);
}